// Round 9
// baseline (5262.231 us; speedup 1.0000x reference)
//
#include <hip/hip_runtime.h>
#include <cstdint>

typedef short bf16x8 __attribute__((ext_vector_type(8)));
typedef float f32x4  __attribute__((ext_vector_type(4)));
typedef unsigned u32x4 __attribute__((ext_vector_type(4)));

constexpr int Bn = 16, Tn = 2048, Dn = 512, Hn = 512;
constexpr int NWG = 16, JWG = 32, NTH = 512;
constexpr int NLAUNCH = 128;   // election pool
constexpr int TC1 = 16;        // timesteps per pass-1 workgroup

#define MFMA16(a, b, c) __builtin_amdgcn_mfma_f32_16x16x32_bf16((a), (b), (c), 0, 0, 0)

#define POLLS_FAST() do { \
  asm volatile("global_load_dwordx4 %0, %1, off sc0 nt" : "=v"(a0) : "v"(hpF)      : "memory"); \
  asm volatile("global_load_dwordx4 %0, %1, off sc0 nt" : "=v"(a1) : "v"(hpF + 16) : "memory"); \
  asm volatile("global_load_dwordx4 %0, %1, off sc0 nt" : "=v"(a2) : "v"(hpF + 32) : "memory"); \
  asm volatile("global_load_dwordx4 %0, %1, off sc0 nt" : "=v"(a3) : "v"(hpF + 48) : "memory"); \
} while (0)
#define POLLS_SLOW() do { \
  asm volatile("global_load_dwordx4 %0, %1, off sc0 sc1" : "=v"(a0) : "v"(hpS)      : "memory"); \
  asm volatile("global_load_dwordx4 %0, %1, off sc0 sc1" : "=v"(a1) : "v"(hpS + 16) : "memory"); \
  asm volatile("global_load_dwordx4 %0, %1, off sc0 sc1" : "=v"(a2) : "v"(hpS + 32) : "memory"); \
  asm volatile("global_load_dwordx4 %0, %1, off sc0 sc1" : "=v"(a3) : "v"(hpS + 48) : "memory"); \
} while (0)
#define PUBS_PEND(slot_t) do { \
  if (!(jj & 1)) { \
    unsigned* dstS_ = ringS + (size_t)((slot_t) & 1) * (Bn * Hn / 2) + ((bq * Hn + jg) >> 1); \
    asm volatile("global_store_dword %0, %1, off sc0 sc1" :: "v"(dstS_), "v"(pendP) : "memory"); \
  } \
} while (0)

__device__ __forceinline__ unsigned short f2bf(float f) {
  union { float f; unsigned u; } v; v.f = f;
  unsigned r = v.u + 0x7FFFu + ((v.u >> 16) & 1u);   // RNE
  return (unsigned short)(r >> 16);
}
__device__ __forceinline__ float lo2f(unsigned u) { union { unsigned u; float f; } v; v.u = u << 16;        return v.f; }
__device__ __forceinline__ float hi2f(unsigned u) { union { unsigned u; float f; } v; v.u = u & 0xFFFF0000u; return v.f; }
__device__ __forceinline__ float asf(unsigned u)  { union { unsigned u; float f; } v; v.u = u; return v.f; }
__device__ __forceinline__ unsigned asu(float f)  { union { float f; unsigned u; } v; v.f = f; return v.u; }

// ============ pass 1: x_proj = x @ w_ih^T + b_ih (+ b_hh for r,z), bf16 ============
__global__ __launch_bounds__(NTH, 2) void xproj_pass(
    const float* __restrict__ x, const float* __restrict__ w_ih,
    const float* __restrict__ b_ih, const float* __restrict__ b_hh,
    unsigned* __restrict__ xrz, unsigned short* __restrict__ xnb)
{
  const int tid = threadIdx.x, lane = tid & 63, wv = tid >> 6;
  const int kw = wv & 3, jw = wv >> 2;
  const int arow = lane & 15, koff = (lane >> 4) * 8;
  const int wg = blockIdx.x, t0 = blockIdx.y * TC1;
  const int kb = kw * 128;

  bf16x8 wif[3][4];
  #pragma unroll
  for (int g = 0; g < 3; ++g) {
    const int grow = g * Hn + wg * JWG + jw * 16 + arow;
    #pragma unroll
    for (int s = 0; s < 4; ++s) {
      const float* pi = w_ih + (size_t)grow * Dn + kb + s * 32 + koff;
      bf16x8 b;
      #pragma unroll
      for (int i = 0; i < 8; ++i) b[i] = (short)f2bf(pi[i]);
      wif[g][s] = b;
    }
  }
  const int bq = tid >> 5, jj = tid & 31, jg = wg * JWG + jj;
  const float br = b_ih[jg]          + b_hh[jg];
  const float bz = b_ih[Hn + jg]     + b_hh[Hn + jg];
  const float bn = b_ih[2 * Hn + jg];                  // b_hh[n] stays in pass 2

  __shared__ float red[3][4][16][32];
  const float* xrow = x + (size_t)arow * Tn * Dn + kb + koff;

  for (int tt = 0; tt < TC1; ++tt) {
    const int t = t0 + tt;
    const float* xt = xrow + (size_t)t * Dn;
    f32x4 xa[4][2];
    #pragma unroll
    for (int s = 0; s < 4; ++s) {
      xa[s][0] = *(const f32x4*)(xt + s * 32);
      xa[s][1] = *(const f32x4*)(xt + s * 32 + 4);
    }
    bf16x8 xf[4];
    #pragma unroll
    for (int s = 0; s < 4; ++s) {
      unsigned d0, d1, d2, d3;
      asm("v_cvt_pk_bf16_f32 %0, %1, %2" : "=v"(d0) : "v"(xa[s][0][0]), "v"(xa[s][0][1]));
      asm("v_cvt_pk_bf16_f32 %0, %1, %2" : "=v"(d1) : "v"(xa[s][0][2]), "v"(xa[s][0][3]));
      asm("v_cvt_pk_bf16_f32 %0, %1, %2" : "=v"(d2) : "v"(xa[s][1][0]), "v"(xa[s][1][1]));
      asm("v_cvt_pk_bf16_f32 %0, %1, %2" : "=v"(d3) : "v"(xa[s][1][2]), "v"(xa[s][1][3]));
      union { u32x4 u; bf16x8 v; } xu;
      xu.u[0] = d0; xu.u[1] = d1; xu.u[2] = d2; xu.u[3] = d3;
      xf[s] = xu.v;
    }
    f32x4 ar = {0,0,0,0}, az = {0,0,0,0}, an = {0,0,0,0};
    #pragma unroll
    for (int s = 0; s < 4; ++s) {
      ar = MFMA16(xf[s], wif[0][s], ar);
      az = MFMA16(xf[s], wif[1][s], az);
      an = MFMA16(xf[s], wif[2][s], an);
    }
    #pragma unroll
    for (int i = 0; i < 4; ++i) {
      const int r_ = (lane >> 4) * 4 + i, c_ = jw * 16 + (lane & 15);
      red[0][kw][r_][c_] = ar[i];
      red[1][kw][r_][c_] = az[i];
      red[2][kw][r_][c_] = an[i];
    }
    __syncthreads();
    float sr = br, sz = bz, sn = bn;
    #pragma unroll
    for (int k2 = 0; k2 < 4; ++k2) {
      sr += red[0][k2][bq][jj];
      sz += red[1][k2][bq][jj];
      sn += red[2][k2][bq][jj];
    }
    unsigned rz;
    asm("v_cvt_pk_bf16_f32 %0, %1, %2" : "=v"(rz) : "v"(sr), "v"(sz));
    const size_t o = (size_t)(wg * Tn + t) * 512 + tid;
    xrz[o] = rz;
    xnb[o] = f2bf(sn);
    __syncthreads();
  }
}

// ============ pass 2: recurrence — clean-queue intra-XCD ring + LLC ring ============
template<bool XP>
__global__ __launch_bounds__(NTH, 2) void gru_scan(
    const float* __restrict__ x, const int* __restrict__ start,
    const float* __restrict__ w_ih, const float* __restrict__ w_hh,
    const float* __restrict__ b_ih, const float* __restrict__ b_hh,
    float* __restrict__ out, unsigned* __restrict__ ectl,
    unsigned* __restrict__ ringF, unsigned* __restrict__ ringS,
    const unsigned* __restrict__ xrz, const unsigned short* __restrict__ xnb)
{
  // ---- election (R7/R8-proven: co-locates 16 workers on WG0's XCD) ----
  __shared__ int s_rank;
  __shared__ int s_fastok;
  if (threadIdx.x == 0) {
    unsigned xcc;
    asm volatile("s_getreg_b32 %0, hwreg(HW_REG_XCC_ID)" : "=s"(xcc));
    xcc &= 7u;
    if (blockIdx.x == 0)
      __hip_atomic_store(&ectl[8], xcc | 0x100u, __ATOMIC_RELAXED, __HIP_MEMORY_SCOPE_AGENT);
    unsigned w;
    while ((((w = __hip_atomic_load(&ectl[8], __ATOMIC_RELAXED, __HIP_MEMORY_SCOPE_AGENT))) & 0x100u) == 0u)
      __builtin_amdgcn_s_sleep(2);
    if ((w & 7u) != xcc)                       // remote: delay before claiming leftovers
      for (int i = 0; i < 800; ++i) __builtin_amdgcn_s_sleep(2);
    const unsigned slot =
        __hip_atomic_fetch_add(&ectl[9], 1u, __ATOMIC_RELAXED, __HIP_MEMORY_SCOPE_AGENT);
    s_rank = (slot < (unsigned)NWG) ? (int)slot : -1;
  }
  __syncthreads();
  const int rank = s_rank;
  if (rank < 0) return;

  const int tid = threadIdx.x, lane = tid & 63, wv = tid >> 6;
  const int kw = wv & 3, jw = wv >> 2;
  const int arow = lane & 15, koff = (lane >> 4) * 8;
  const int kb = kw * 128;
  constexpr int NG = XP ? 3 : 4;

  bf16x8 whf[3][4], wif[3][4];
  #pragma unroll
  for (int g = 0; g < 3; ++g) {
    const int grow = g * Hn + rank * JWG + jw * 16 + arow;
    #pragma unroll
    for (int s = 0; s < 4; ++s) {
      const float* ph = w_hh + (size_t)grow * Dn + kb + s * 32 + koff;
      bf16x8 a;
      #pragma unroll
      for (int i = 0; i < 8; ++i) a[i] = (short)f2bf(ph[i]);
      whf[g][s] = a;
      if constexpr (!XP) {
        const float* pi = w_ih + (size_t)grow * Dn + kb + s * 32 + koff;
        bf16x8 b;
        #pragma unroll
        for (int i = 0; i < 8; ++i) b[i] = (short)f2bf(pi[i]);
        wif[g][s] = b;
      }
    }
  }

  // ---- coherence probe (exact fast-poll load type) + rendezvous (R8-proven) ----
  if (threadIdx.x == 0) {
    if (rank == 0) {
      const unsigned* tp = &ectl[32];
      asm volatile("global_store_dword %0, %1, off" :: "v"(tp), "v"(0xA5A5A5A5u) : "memory");
      asm volatile("s_waitcnt vmcnt(0)" ::: "memory");
      __hip_atomic_store(&ectl[10], 1u, __ATOMIC_RELAXED, __HIP_MEMORY_SCOPE_AGENT);
    }
    while (__hip_atomic_load(&ectl[10], __ATOMIC_RELAXED, __HIP_MEMORY_SCOPE_AGENT) == 0u)
      __builtin_amdgcn_s_sleep(1);
    int ok = 0;
    const unsigned* tp = &ectl[32];
    for (int i = 0; i < 1024 && !ok; ++i) {
      unsigned tok;
      asm volatile("global_load_dword %0, %1, off sc0 nt" : "=v"(tok) : "v"(tp) : "memory");
      asm volatile("s_waitcnt vmcnt(0)" ::: "memory");
      ok = (tok == 0xA5A5A5A5u);
      if (!ok && (i & 15) == 15) __builtin_amdgcn_s_sleep(1);
    }
    s_fastok = ok;
    __hip_atomic_store(&ectl[64 + rank], 1u, __ATOMIC_RELAXED, __HIP_MEMORY_SCOPE_AGENT);
    for (;;) {
      unsigned rdy = 0;
      for (int i = 0; i < 16; ++i)
        rdy += __hip_atomic_load(&ectl[64 + i], __ATOMIC_RELAXED, __HIP_MEMORY_SCOPE_AGENT);
      if (rdy == 16u) break;
      __builtin_amdgcn_s_sleep(1);
    }
  }
  __syncthreads();
  bool fastwave = (s_fastok != 0);            // per-wave sticky state

  const int bq = tid >> 5, jj = tid & 31, jg = rank * JWG + jj;
  const float bias_nh = b_hh[2 * Hn + jg];
  float bias_r = 0.f, bias_z = 0.f, bias_nx = 0.f;
  if constexpr (!XP) {
    bias_r  = b_ih[jg]      + b_hh[jg];
    bias_z  = b_ih[Hn + jg] + b_hh[Hn + jg];
    bias_nx = b_ih[2 * Hn + jg];
  }
  const int start_g = start[bq];
  const int start_a = start[arow];
  // C-native reduce-read mapping
  const int jwr  = jj >> 4;
  const int lsrc = ((bq >> 2) << 4) | (jj & 15);
  const int ib   = bq & 3;

  float h_own = 0.f;
  unsigned po0u = 0u, po1u = 0u;                        // delayed out stores
  unsigned pendP = 0u;                                  // deferred slow-ring publish
  __shared__ float red[2][NG][4][2][64][4];             // [par][gate][kw][jw][lane][reg]

  const float*          xres_p = x   + (size_t)bq * Tn * Dn + jg;
  const unsigned*       xrz_p  = xrz + (size_t)rank * Tn * 512 + tid;
  const unsigned short* xn_p   = xnb + (size_t)rank * Tn * 512 + tid;
  const float*          xrow   = x   + (size_t)arow * Tn * Dn + kb + koff;

  unsigned prz0=0, prz1=0, prz2=0, prz3=0, pn0=0, pn1=0, pn2=0, pn3=0;
  unsigned pxr0=0, pxr1=0, pxr2=0, pxr3=0;
  f32x4 xa0[4][2], xa1[4][2]; float xr0 = 0.f, xr1 = 0.f;
  if constexpr (XP) {
    prz0 = xrz_p[0];   pn0 = xn_p[0];
    prz1 = xrz_p[512]; pn1 = xn_p[512];
    pxr0 = asu(xres_p[0]); pxr1 = asu(xres_p[Dn]);
  } else {
    #pragma unroll
    for (int s = 0; s < 4; ++s) {
      xa0[s][0] = *(const f32x4*)(xrow + s * 32);
      xa0[s][1] = *(const f32x4*)(xrow + s * 32 + 4);
      xa1[s][0] = *(const f32x4*)(xrow + (size_t)Dn + s * 32);
      xa1[s][1] = *(const f32x4*)(xrow + (size_t)Dn + s * 32 + 4);
    }
    xr0 = xres_p[0]; xr1 = xres_p[Dn];
  }

  auto step = [&](int t, unsigned& crz, unsigned& cn, unsigned& cxr,
                  unsigned& frz, unsigned& fn, unsigned& fxr,
                  f32x4 (&xa)[4][2], float& xr) {
    const bool hv = (t > 0);
    const float xres_t = XP ? asf(cxr) : xr;
    f32x4 ar = {0,0,0,0}, az = {0,0,0,0}, anx = {0,0,0,0}, anh = {0,0,0,0};

    if constexpr (!XP) {    // phase A: input projection from registers
      bf16x8 xf[4];
      #pragma unroll
      for (int s = 0; s < 4; ++s) {
        unsigned d0, d1, d2, d3;
        asm("v_cvt_pk_bf16_f32 %0, %1, %2" : "=v"(d0) : "v"(xa[s][0][0]), "v"(xa[s][0][1]));
        asm("v_cvt_pk_bf16_f32 %0, %1, %2" : "=v"(d1) : "v"(xa[s][0][2]), "v"(xa[s][0][3]));
        asm("v_cvt_pk_bf16_f32 %0, %1, %2" : "=v"(d2) : "v"(xa[s][1][0]), "v"(xa[s][1][1]));
        asm("v_cvt_pk_bf16_f32 %0, %1, %2" : "=v"(d3) : "v"(xa[s][1][2]), "v"(xa[s][1][3]));
        union { u32x4 u; bf16x8 v; } xu;
        xu.u[0] = d0; xu.u[1] = d1; xu.u[2] = d2; xu.u[3] = d3;
        xf[s] = xu.v;
      }
      #pragma unroll
      for (int s = 0; s < 4; ++s) {
        ar  = MFMA16(xf[s], wif[0][s], ar);
        az  = MFMA16(xf[s], wif[1][s], az);
        anx = MFMA16(xf[s], wif[2][s], anx);
      }
    }

    // ---- pre-validate zone: POLLS ONLY (clean vm queue -> every wait ~ 1 L2 RT).
    //      Slow waves must also publish pendP here (all-slow liveness). ----
    const size_t off_h = (size_t)(t & 1) * (Bn * Hn / 2) + ((arow * Hn + kb + koff) >> 1);
    const unsigned* hpF = ringF + off_h;
    const unsigned* hpS = ringS + off_h;
    u32x4 a0, a1, a2, a3;
    if (hv) {
      if (!fastwave) PUBS_PEND(t);            // gen t -> buf[t&1], before validate
      if (fastwave) POLLS_FAST(); else POLLS_SLOW();
      asm volatile("s_waitcnt vmcnt(0)" ::: "memory");
      __builtin_amdgcn_sched_barrier(0);
      const unsigned pexp = (unsigned)((t >> 1) & 1);
      int tries = 0;
      for (;;) {
        int ok;
        if (pexp) {
          const unsigned andv = a0[0] & a0[1] & a0[2] & a0[3] & a1[0] & a1[1] & a1[2] & a1[3]
                              & a2[0] & a2[1] & a2[2] & a2[3] & a3[0] & a3[1] & a3[2] & a3[3];
          ok = ((andv & 0x00010001u) == 0x00010001u);
        } else {
          const unsigned orv  = a0[0] | a0[1] | a0[2] | a0[3] | a1[0] | a1[1] | a1[2] | a1[3]
                              | a2[0] | a2[1] | a2[2] | a2[3] | a3[0] | a3[1] | a3[2] | a3[3];
          ok = ((orv & 0x00010001u) == 0u);
        }
        if (__all(ok)) break;
        ++tries;
        if (fastwave && tries >= 8192) {      // insurance: degrade, publish, never hang
          fastwave = false;
          PUBS_PEND(t);
        }
        if (!fastwave || tries > 32) __builtin_amdgcn_s_sleep(1);
        if (fastwave) POLLS_FAST(); else POLLS_SLOW();
        asm volatile("s_waitcnt vmcnt(0)" ::: "memory");
        __builtin_amdgcn_sched_barrier(0);
      }
    }

    // ---- hidden projection MFMAs ----
    if (hv) {
      const bool am = (start_a < t);
      union { u32x4 u; bf16x8 v; } c0, c1, c2, c3;
      const u32x4 zz = {0, 0, 0, 0};
      c0.u = am ? a0 : zz; c1.u = am ? a1 : zz; c2.u = am ? a2 : zz; c3.u = am ? a3 : zz;
      ar  = MFMA16(c0.v, whf[0][0], ar);  az  = MFMA16(c0.v, whf[1][0], az);
      anh = MFMA16(c0.v, whf[2][0], anh);
      ar  = MFMA16(c1.v, whf[0][1], ar);  az  = MFMA16(c1.v, whf[1][1], az);
      anh = MFMA16(c1.v, whf[2][1], anh);
      ar  = MFMA16(c2.v, whf[0][2], ar);  az  = MFMA16(c2.v, whf[1][2], az);
      anh = MFMA16(c2.v, whf[2][2], anh);
      ar  = MFMA16(c3.v, whf[0][3], ar);  az  = MFMA16(c3.v, whf[1][3], az);
      anh = MFMA16(c3.v, whf[2][3], anh);
    }

    // ---- reduce: C-native b128 writes, barrier with EMPTY vm queue ----
    const int par = t & 1;
    *(f32x4*)&red[par][0][kw][jw][lane][0] = ar;
    *(f32x4*)&red[par][1][kw][jw][lane][0] = az;
    if constexpr (XP) {
      *(f32x4*)&red[par][2][kw][jw][lane][0] = anh;
    } else {
      *(f32x4*)&red[par][2][kw][jw][lane][0] = anx;
      *(f32x4*)&red[par][3][kw][jw][lane][0] = anh;
    }
    __syncthreads();

    // ---- post-barrier bundle: slow ops get a full step to retire ----
    if constexpr (XP) {
      const int tf = (t + 2 < Tn) ? t + 2 : Tn - 1;
      const unsigned*       p1 = xrz_p + (size_t)tf * 512;
      const unsigned short* p2 = xn_p  + (size_t)tf * 512;
      const float*          p3 = xres_p + (size_t)tf * Dn;
      asm volatile("global_load_dword  %0, %1, off" : "=v"(frz) : "v"(p1) : "memory");
      asm volatile("global_load_ushort %0, %1, off" : "=v"(fn)  : "v"(p2) : "memory");
      asm volatile("global_load_dword  %0, %1, off" : "=v"(fxr) : "v"(p3) : "memory");
    } else {
      const int tf = (t + 2 < Tn) ? t + 2 : Tn - 1;
      const float* xt = xrow + (size_t)tf * Dn;
      #pragma unroll
      for (int s = 0; s < 4; ++s) {
        xa[s][0] = *(const f32x4*)(xt + s * 32);
        xa[s][1] = *(const f32x4*)(xt + s * 32 + 4);
      }
      xr = xres_p[(size_t)tf * Dn];
    }
    if (hv) {             // delayed out stores for t-1
      const size_t poo = ((size_t)bq * Tn + (t - 1)) * Hn + jg;
      const float* q0 = out + poo;
      const float* q1 = out + (size_t)Bn * Tn * Hn + poo;
      asm volatile("global_store_dword %0, %1, off" :: "v"(q0), "v"(po0u) : "memory");
      asm volatile("global_store_dword %0, %1, off" :: "v"(q1), "v"(po1u) : "memory");
    }
    if (hv && fastwave) PUBS_PEND(t);         // fast waves: slow copy off critical path

    // ---- reduce reads + gates ----
    float sr, sz, snx, snh;
    if constexpr (XP) { sr = lo2f(crz); sz = hi2f(crz); snx = lo2f(cn); snh = bias_nh; }
    else              { sr = bias_r;    sz = bias_z;    snx = bias_nx;  snh = bias_nh; }
    #pragma unroll
    for (int k2 = 0; k2 < 4; ++k2) {
      sr += red[par][0][k2][jwr][lsrc][ib];
      sz += red[par][1][k2][jwr][lsrc][ib];
      if constexpr (XP) {
        snh += red[par][2][k2][jwr][lsrc][ib];
      } else {
        snx += red[par][2][k2][jwr][lsrc][ib];
        snh += red[par][3][k2][jwr][lsrc][ib];
      }
    }
    const float r  = 1.f / (1.f + __expf(-sr));
    const float z  = 1.f / (1.f + __expf(-sz));
    const float ea = __expf(2.f * (snx + r * snh));
    const float n  = 1.f - 2.f / (ea + 1.f);             // NaN-safe tanh
    const float hm = (start_g < t) ? h_own : 0.f;
    const float hn = (1.f - z) * n + z * hm;
    h_own = hn;

    // ---- pack (cvt_pk) + fast publish of gen t+1 ----
    const unsigned ptag01 = (unsigned)(((t + 1) >> 1) & 1) * 0x00010001u;
    const float hpart = asf((unsigned)__shfl_xor((int)asu(hn), 1, 64));
    unsigned packed;
    asm("v_cvt_pk_bf16_f32 %0, %1, %2" : "=v"(packed) : "v"(hn), "v"(hpart));
    packed = (packed & 0xFFFEFFFEu) | ptag01;
    if (!(jj & 1)) {
      unsigned* dstF = ringF + (size_t)((t + 1) & 1) * (Bn * Hn / 2) + ((bq * Hn + jg) >> 1);
      asm volatile("global_store_dword %0, %1, off" :: "v"(dstF), "v"(packed) : "memory");
    }
    pendP = packed;

    po0u = asu(xres_t + hn);
    po1u = asu(hn);
  };

  #pragma unroll 1
  for (int t = 0; t < Tn; t += 4) {
    step(t + 0, prz0, pn0, pxr0, prz2, pn2, pxr2, xa0, xr0);
    step(t + 1, prz1, pn1, pxr1, prz3, pn3, pxr3, xa1, xr1);
    step(t + 2, prz2, pn2, pxr2, prz0, pn0, pxr0, xa0, xr0);
    step(t + 3, prz3, pn3, pxr3, prz1, pn1, pxr1, xa1, xr1);
  }
  {   // final outputs (t = Tn-1)
    const size_t poo = ((size_t)bq * Tn + (Tn - 1)) * Hn + jg;
    out[poo] = asf(po0u);
    out[(size_t)Bn * Tn * Hn + poo] = asf(po1u);
  }
}

extern "C" void kernel_launch(void* const* d_in, const int* in_sizes, int n_in,
                              void* d_out, int out_size, void* d_ws, size_t ws_size,
                              hipStream_t stream) {
  const float* x     = (const float*)d_in[0];
  const int*   start = (const int*)d_in[1];
  const float* w_ih  = (const float*)d_in[2];
  const float* w_hh  = (const float*)d_in[3];
  const float* b_ih  = (const float*)d_in[4];
  const float* b_hh  = (const float*)d_in[5];
  float* out = (float*)d_out;

  // ws: [0,4K) ectl | [4K,+32K) fast ring | [36K,+32K) slow ring | [128K,+64M) xrz | +32M xnb
  unsigned* ectl  = (unsigned*)d_ws;
  unsigned* ringF = (unsigned*)((char*)d_ws + 4096);
  unsigned* ringS = (unsigned*)((char*)d_ws + 36864);
  const size_t xrz_off   = 131072;
  const size_t xrz_bytes = (size_t)NWG * Tn * 512 * 4;   // 64 MiB
  const size_t xn_bytes  = (size_t)NWG * Tn * 512 * 2;   // 32 MiB
  unsigned*       xrz = (unsigned*)((char*)d_ws + xrz_off);
  unsigned short* xnb = (unsigned short*)((char*)d_ws + xrz_off + xrz_bytes);
  const bool xp = ws_size >= xrz_off + xrz_bytes + xn_bytes;

  // Parity init per ring: buf0 LSB=0 (first read t=2 expects 1), buf1 LSB=1
  // (first read t=1 expects 0). Stale replay generations never false-validate.
  // Election/probe/ready state zeroed each launch. All graph-capture-safe.
  hipMemsetAsync(d_ws, 0x00, 4096, stream);
  hipMemsetAsync((char*)d_ws + 4096,  0x00, 16384, stream);
  hipMemsetAsync((char*)d_ws + 20480, 0x01, 16384, stream);
  hipMemsetAsync((char*)d_ws + 36864, 0x00, 16384, stream);
  hipMemsetAsync((char*)d_ws + 53248, 0x01, 16384, stream);
  if (xp) {
    hipLaunchKernelGGL(xproj_pass, dim3(NWG, Tn / TC1), dim3(NTH), 0, stream,
                       x, w_ih, b_ih, b_hh, xrz, xnb);
    hipLaunchKernelGGL(gru_scan<true>, dim3(NLAUNCH), dim3(NTH), 0, stream,
                       x, start, w_ih, w_hh, b_ih, b_hh, out, ectl, ringF, ringS, xrz, xnb);
  } else {
    hipLaunchKernelGGL(gru_scan<false>, dim3(NLAUNCH), dim3(NTH), 0, stream,
                       x, start, w_ih, w_hh, b_ih, b_hh, out, ectl, ringF, ringS,
                       (const unsigned*)d_ws, (const unsigned short*)d_ws);
  }
}

// Round 10
// 4693.369 us; speedup vs baseline: 1.1212x; 1.1212x over previous
//
#include <hip/hip_runtime.h>
#include <cstdint>

typedef short bf16x8 __attribute__((ext_vector_type(8)));
typedef float f32x4  __attribute__((ext_vector_type(4)));
typedef unsigned u32x4 __attribute__((ext_vector_type(4)));

constexpr int Bn = 16, Tn = 2048, Dn = 512, Hn = 512;
constexpr int NWG = 16, JWG = 32, NTH = 512;
constexpr int NLAUNCH = 128;   // election pool
constexpr int TC1 = 16;        // timesteps per pass-1 workgroup

#define MFMA16(a, b, c) __builtin_amdgcn_mfma_f32_16x16x32_bf16((a), (b), (c), 0, 0, 0)

#define POLLS_FAST() do { \
  asm volatile("global_load_dwordx4 %0, %1, off sc0 nt" : "=v"(a0) : "v"(hpF)      : "memory"); \
  asm volatile("global_load_dwordx4 %0, %1, off sc0 nt" : "=v"(a1) : "v"(hpF + 16) : "memory"); \
  asm volatile("global_load_dwordx4 %0, %1, off sc0 nt" : "=v"(a2) : "v"(hpF + 32) : "memory"); \
  asm volatile("global_load_dwordx4 %0, %1, off sc0 nt" : "=v"(a3) : "v"(hpF + 48) : "memory"); \
} while (0)
#define POLLS_SLOW() do { \
  asm volatile("global_load_dwordx4 %0, %1, off sc0 sc1" : "=v"(a0) : "v"(hpS)      : "memory"); \
  asm volatile("global_load_dwordx4 %0, %1, off sc0 sc1" : "=v"(a1) : "v"(hpS + 16) : "memory"); \
  asm volatile("global_load_dwordx4 %0, %1, off sc0 sc1" : "=v"(a2) : "v"(hpS + 32) : "memory"); \
  asm volatile("global_load_dwordx4 %0, %1, off sc0 sc1" : "=v"(a3) : "v"(hpS + 48) : "memory"); \
} while (0)

__device__ __forceinline__ unsigned short f2bf(float f) {
  union { float f; unsigned u; } v; v.f = f;
  unsigned r = v.u + 0x7FFFu + ((v.u >> 16) & 1u);   // RNE
  return (unsigned short)(r >> 16);
}
__device__ __forceinline__ float lo2f(unsigned u) { union { unsigned u; float f; } v; v.u = u << 16;        return v.f; }
__device__ __forceinline__ float hi2f(unsigned u) { union { unsigned u; float f; } v; v.u = u & 0xFFFF0000u; return v.f; }
__device__ __forceinline__ float asf(unsigned u)  { union { unsigned u; float f; } v; v.u = u; return v.f; }
__device__ __forceinline__ unsigned asu(float f)  { union { float f; unsigned u; } v; v.f = f; return v.u; }

// ============ pass 1: x_proj = x @ w_ih^T + b_ih (+ b_hh for r,z), bf16 ============
__global__ __launch_bounds__(NTH, 2) void xproj_pass(
    const float* __restrict__ x, const float* __restrict__ w_ih,
    const float* __restrict__ b_ih, const float* __restrict__ b_hh,
    unsigned* __restrict__ xrz, unsigned short* __restrict__ xnb)
{
  const int tid = threadIdx.x, lane = tid & 63, wv = tid >> 6;
  const int kw = wv & 3, jw = wv >> 2;
  const int arow = lane & 15, koff = (lane >> 4) * 8;
  const int wg = blockIdx.x, t0 = blockIdx.y * TC1;
  const int kb = kw * 128;

  bf16x8 wif[3][4];
  #pragma unroll
  for (int g = 0; g < 3; ++g) {
    const int grow = g * Hn + wg * JWG + jw * 16 + arow;
    #pragma unroll
    for (int s = 0; s < 4; ++s) {
      const float* pi = w_ih + (size_t)grow * Dn + kb + s * 32 + koff;
      bf16x8 b;
      #pragma unroll
      for (int i = 0; i < 8; ++i) b[i] = (short)f2bf(pi[i]);
      wif[g][s] = b;
    }
  }
  const int bq = tid >> 5, jj = tid & 31, jg = wg * JWG + jj;
  const float br = b_ih[jg]          + b_hh[jg];
  const float bz = b_ih[Hn + jg]     + b_hh[Hn + jg];
  const float bn = b_ih[2 * Hn + jg];                  // b_hh[n] stays in pass 2

  __shared__ float red[3][4][16][32];
  const float* xrow = x + (size_t)arow * Tn * Dn + kb + koff;

  for (int tt = 0; tt < TC1; ++tt) {
    const int t = t0 + tt;
    const float* xt = xrow + (size_t)t * Dn;
    f32x4 xa[4][2];
    #pragma unroll
    for (int s = 0; s < 4; ++s) {
      xa[s][0] = *(const f32x4*)(xt + s * 32);
      xa[s][1] = *(const f32x4*)(xt + s * 32 + 4);
    }
    bf16x8 xf[4];
    #pragma unroll
    for (int s = 0; s < 4; ++s) {
      unsigned d0, d1, d2, d3;
      asm("v_cvt_pk_bf16_f32 %0, %1, %2" : "=v"(d0) : "v"(xa[s][0][0]), "v"(xa[s][0][1]));
      asm("v_cvt_pk_bf16_f32 %0, %1, %2" : "=v"(d1) : "v"(xa[s][0][2]), "v"(xa[s][0][3]));
      asm("v_cvt_pk_bf16_f32 %0, %1, %2" : "=v"(d2) : "v"(xa[s][1][0]), "v"(xa[s][1][1]));
      asm("v_cvt_pk_bf16_f32 %0, %1, %2" : "=v"(d3) : "v"(xa[s][1][2]), "v"(xa[s][1][3]));
      union { u32x4 u; bf16x8 v; } xu;
      xu.u[0] = d0; xu.u[1] = d1; xu.u[2] = d2; xu.u[3] = d3;
      xf[s] = xu.v;
    }
    f32x4 ar = {0,0,0,0}, az = {0,0,0,0}, an = {0,0,0,0};
    #pragma unroll
    for (int s = 0; s < 4; ++s) {
      ar = MFMA16(xf[s], wif[0][s], ar);
      az = MFMA16(xf[s], wif[1][s], az);
      an = MFMA16(xf[s], wif[2][s], an);
    }
    #pragma unroll
    for (int i = 0; i < 4; ++i) {
      const int r_ = (lane >> 4) * 4 + i, c_ = jw * 16 + (lane & 15);
      red[0][kw][r_][c_] = ar[i];
      red[1][kw][r_][c_] = az[i];
      red[2][kw][r_][c_] = an[i];
    }
    __syncthreads();
    float sr = br, sz = bz, sn = bn;
    #pragma unroll
    for (int k2 = 0; k2 < 4; ++k2) {
      sr += red[0][k2][bq][jj];
      sz += red[1][k2][bq][jj];
      sn += red[2][k2][bq][jj];
    }
    unsigned rz;
    asm("v_cvt_pk_bf16_f32 %0, %1, %2" : "=v"(rz) : "v"(sr), "v"(sz));
    const size_t o = (size_t)(wg * Tn + t) * 512 + tid;
    xrz[o] = rz;
    xnb[o] = f2bf(sn);
    __syncthreads();
  }
}

// ============ pass 2: recurrence — single-mode ring (probe-decided) ============
template<bool XP>
__global__ __launch_bounds__(NTH, 2) void gru_scan(
    const float* __restrict__ x, const int* __restrict__ start,
    const float* __restrict__ w_ih, const float* __restrict__ w_hh,
    const float* __restrict__ b_ih, const float* __restrict__ b_hh,
    float* __restrict__ out, unsigned* __restrict__ ectl,
    unsigned* __restrict__ ringF, unsigned* __restrict__ ringS,
    const unsigned* __restrict__ xrz, const unsigned short* __restrict__ xnb)
{
  // ---- election (R7/R8-proven: co-locates 16 workers on WG0's XCD) ----
  __shared__ int s_rank;
  __shared__ int s_fast;
  if (threadIdx.x == 0) {
    unsigned xcc;
    asm volatile("s_getreg_b32 %0, hwreg(HW_REG_XCC_ID)" : "=s"(xcc));
    xcc &= 7u;
    if (blockIdx.x == 0)
      __hip_atomic_store(&ectl[8], xcc | 0x100u, __ATOMIC_RELAXED, __HIP_MEMORY_SCOPE_AGENT);
    unsigned w;
    while ((((w = __hip_atomic_load(&ectl[8], __ATOMIC_RELAXED, __HIP_MEMORY_SCOPE_AGENT))) & 0x100u) == 0u)
      __builtin_amdgcn_s_sleep(2);
    if ((w & 7u) != xcc)                       // remote: delay before claiming leftovers
      for (int i = 0; i < 800; ++i) __builtin_amdgcn_s_sleep(2);
    const unsigned slot =
        __hip_atomic_fetch_add(&ectl[9], 1u, __ATOMIC_RELAXED, __HIP_MEMORY_SCOPE_AGENT);
    s_rank = (slot < (unsigned)NWG) ? (int)slot : -1;
  }
  __syncthreads();
  const int rank = s_rank;
  if (rank < 0) return;

  const int tid = threadIdx.x, lane = tid & 63, wv = tid >> 6;
  const int kw = wv & 3, jw = wv >> 2;
  const int arow = lane & 15, koff = (lane >> 4) * 8;
  const int kb = kw * 128;
  constexpr int NG = XP ? 3 : 4;

  bf16x8 whf[3][4], wif[3][4];
  #pragma unroll
  for (int g = 0; g < 3; ++g) {
    const int grow = g * Hn + rank * JWG + jw * 16 + arow;
    #pragma unroll
    for (int s = 0; s < 4; ++s) {
      const float* ph = w_hh + (size_t)grow * Dn + kb + s * 32 + koff;
      bf16x8 a;
      #pragma unroll
      for (int i = 0; i < 8; ++i) a[i] = (short)f2bf(ph[i]);
      whf[g][s] = a;
      if constexpr (!XP) {
        const float* pi = w_ih + (size_t)grow * Dn + kb + s * 32 + koff;
        bf16x8 b;
        #pragma unroll
        for (int i = 0; i < 8; ++i) b[i] = (short)f2bf(pi[i]);
        wif[g][s] = b;
      }
    }
  }

  // ---- coherence probe -> GLOBAL mode decision (AND of all 16 ranks) ----
  if (threadIdx.x == 0) {
    if (rank == 0) {
      const unsigned* tp = &ectl[32];
      asm volatile("global_store_dword %0, %1, off" :: "v"(tp), "v"(0xA5A5A5A5u) : "memory");
      asm volatile("s_waitcnt vmcnt(0)" ::: "memory");
      __hip_atomic_store(&ectl[10], 1u, __ATOMIC_RELAXED, __HIP_MEMORY_SCOPE_AGENT);
    }
    while (__hip_atomic_load(&ectl[10], __ATOMIC_RELAXED, __HIP_MEMORY_SCOPE_AGENT) == 0u)
      __builtin_amdgcn_s_sleep(1);
    int ok = 0;
    const unsigned* tp = &ectl[32];
    for (int i = 0; i < 1024 && !ok; ++i) {
      unsigned tok;
      asm volatile("global_load_dword %0, %1, off sc0 nt" : "=v"(tok) : "v"(tp) : "memory");
      asm volatile("s_waitcnt vmcnt(0)" ::: "memory");
      ok = (tok == 0xA5A5A5A5u);
      if (!ok && (i & 15) == 15) __builtin_amdgcn_s_sleep(1);
    }
    __hip_atomic_store(&ectl[64 + rank], ok ? 1u : 2u, __ATOMIC_RELAXED, __HIP_MEMORY_SCOPE_AGENT);
    unsigned andok;
    for (;;) {
      andok = 1u;
      unsigned done = 0;
      for (int i = 0; i < 16; ++i) {
        const unsigned v = __hip_atomic_load(&ectl[64 + i], __ATOMIC_RELAXED, __HIP_MEMORY_SCOPE_AGENT);
        done += (v != 0u);
        andok &= (v == 1u);
      }
      if (done == 16u) break;
      __builtin_amdgcn_s_sleep(1);
    }
    s_fast = (int)andok;                       // same decision in every WG
  }
  __syncthreads();
  const bool fast = (s_fast != 0);

  const int bq = tid >> 5, jj = tid & 31, jg = rank * JWG + jj;
  const float bias_nh = b_hh[2 * Hn + jg];
  float bias_r = 0.f, bias_z = 0.f, bias_nx = 0.f;
  if constexpr (!XP) {
    bias_r  = b_ih[jg]      + b_hh[jg];
    bias_z  = b_ih[Hn + jg] + b_hh[Hn + jg];
    bias_nx = b_ih[2 * Hn + jg];
  }
  const int start_g = start[bq];
  const int start_a = start[arow];
  const int jr = jj ^ (((bq >> 2) & 1) << 4);          // swizzled reduce-read col

  float h_own = 0.f;
  unsigned po0u = 0u, po1u = 0u;                        // delayed out stores
  __shared__ float red[2][NG][4][16][32];               // R6 layout: 0 conflicts

  const float*          xres_p = x   + (size_t)bq * Tn * Dn + jg;
  const unsigned*       xrz_p  = xrz + (size_t)rank * Tn * 512 + tid;
  const unsigned short* xn_p   = xnb + (size_t)rank * Tn * 512 + tid;
  const float*          xrow   = x   + (size_t)arow * Tn * Dn + kb + koff;

  unsigned prz0=0, prz1=0, prz2=0, prz3=0, pn0=0, pn1=0, pn2=0, pn3=0;
  unsigned pxr0=0, pxr1=0, pxr2=0, pxr3=0;
  f32x4 xa0[4][2], xa1[4][2]; float xr0 = 0.f, xr1 = 0.f;
  if constexpr (XP) {
    prz0 = xrz_p[0];   pn0 = xn_p[0];
    prz1 = xrz_p[512]; pn1 = xn_p[512];
    pxr0 = asu(xres_p[0]); pxr1 = asu(xres_p[Dn]);
  } else {
    #pragma unroll
    for (int s = 0; s < 4; ++s) {
      xa0[s][0] = *(const f32x4*)(xrow + s * 32);
      xa0[s][1] = *(const f32x4*)(xrow + s * 32 + 4);
      xa1[s][0] = *(const f32x4*)(xrow + (size_t)Dn + s * 32);
      xa1[s][1] = *(const f32x4*)(xrow + (size_t)Dn + s * 32 + 4);
    }
    xr0 = xres_p[0]; xr1 = xres_p[Dn];
  }

  auto step = [&](int t, unsigned& crz, unsigned& cn, unsigned& cxr,
                  unsigned& frz, unsigned& fn, unsigned& fxr,
                  f32x4 (&xa)[4][2], float& xr) {
    const bool hv = (t > 0);
    const float xres_t = XP ? asf(cxr) : xr;
    f32x4 ar = {0,0,0,0}, az = {0,0,0,0}, anx = {0,0,0,0}, anh = {0,0,0,0};

    if constexpr (!XP) {    // phase A: input projection from registers
      bf16x8 xf[4];
      #pragma unroll
      for (int s = 0; s < 4; ++s) {
        unsigned d0, d1, d2, d3;
        asm("v_cvt_pk_bf16_f32 %0, %1, %2" : "=v"(d0) : "v"(xa[s][0][0]), "v"(xa[s][0][1]));
        asm("v_cvt_pk_bf16_f32 %0, %1, %2" : "=v"(d1) : "v"(xa[s][0][2]), "v"(xa[s][0][3]));
        asm("v_cvt_pk_bf16_f32 %0, %1, %2" : "=v"(d2) : "v"(xa[s][1][0]), "v"(xa[s][1][1]));
        asm("v_cvt_pk_bf16_f32 %0, %1, %2" : "=v"(d3) : "v"(xa[s][1][2]), "v"(xa[s][1][3]));
        union { u32x4 u; bf16x8 v; } xu;
        xu.u[0] = d0; xu.u[1] = d1; xu.u[2] = d2; xu.u[3] = d3;
        xf[s] = xu.v;
      }
      #pragma unroll
      for (int s = 0; s < 4; ++s) {
        ar  = MFMA16(xf[s], wif[0][s], ar);
        az  = MFMA16(xf[s], wif[1][s], az);
        anx = MFMA16(xf[s], wif[2][s], anx);
      }
    }

    // ---- poll + validate. Fast ledger: queue [pf3,pubF1 | polls4 | outs2]
    //      -> vmcnt(2) retires polls; retries vmcnt(0) drain only outs. ----
    const size_t off_h = (size_t)(t & 1) * (Bn * Hn / 2) + ((arow * Hn + kb + koff) >> 1);
    const unsigned* hpF = ringF + off_h;
    const unsigned* hpS = ringS + off_h;
    u32x4 a0, a1, a2, a3;
    if (hv) {
      if (fast) POLLS_FAST(); else POLLS_SLOW();
      {   // delayed out stores for t-1 (younger than polls)
        const size_t poo = ((size_t)bq * Tn + (t - 1)) * Hn + jg;
        const float* q0 = out + poo;
        const float* q1 = out + (size_t)Bn * Tn * Hn + poo;
        asm volatile("global_store_dword %0, %1, off" :: "v"(q0), "v"(po0u) : "memory");
        asm volatile("global_store_dword %0, %1, off" :: "v"(q1), "v"(po1u) : "memory");
      }
      if (fast) { asm volatile("s_waitcnt vmcnt(2)" ::: "memory"); }
      else      { asm volatile("s_waitcnt vmcnt(0)" ::: "memory"); }
      __builtin_amdgcn_sched_barrier(0);
      const unsigned pexp = (unsigned)((t >> 1) & 1);
      int tries = 0;
      for (;;) {
        int ok;
        if (pexp) {
          const unsigned andv = a0[0] & a0[1] & a0[2] & a0[3] & a1[0] & a1[1] & a1[2] & a1[3]
                              & a2[0] & a2[1] & a2[2] & a2[3] & a3[0] & a3[1] & a3[2] & a3[3];
          ok = ((andv & 0x00010001u) == 0x00010001u);
        } else {
          const unsigned orv  = a0[0] | a0[1] | a0[2] | a0[3] | a1[0] | a1[1] | a1[2] | a1[3]
                              | a2[0] | a2[1] | a2[2] | a2[3] | a3[0] | a3[1] | a3[2] | a3[3];
          ok = ((orv & 0x00010001u) == 0u);
        }
        if (__all(ok)) break;
        ++tries;
        if (!fast || tries > 32) __builtin_amdgcn_s_sleep(1);
        if (fast) POLLS_FAST(); else POLLS_SLOW();
        asm volatile("s_waitcnt vmcnt(0)" ::: "memory");
        __builtin_amdgcn_sched_barrier(0);
      }
    }

    // ---- post-validate prefetch (retires during MFMA/reduce/gates) ----
    if constexpr (XP) {
      const int tf = (t + 2 < Tn) ? t + 2 : Tn - 1;
      const unsigned*       p1 = xrz_p + (size_t)tf * 512;
      const unsigned short* p2 = xn_p  + (size_t)tf * 512;
      const float*          p3 = xres_p + (size_t)tf * Dn;
      asm volatile("global_load_dword  %0, %1, off" : "=v"(frz) : "v"(p1) : "memory");
      asm volatile("global_load_ushort %0, %1, off" : "=v"(fn)  : "v"(p2) : "memory");
      asm volatile("global_load_dword  %0, %1, off" : "=v"(fxr) : "v"(p3) : "memory");
    } else {
      const int tf = (t + 2 < Tn) ? t + 2 : Tn - 1;
      const float* xt = xrow + (size_t)tf * Dn;
      #pragma unroll
      for (int s = 0; s < 4; ++s) {
        xa[s][0] = *(const f32x4*)(xt + s * 32);
        xa[s][1] = *(const f32x4*)(xt + s * 32 + 4);
      }
      xr = xres_p[(size_t)tf * Dn];
    }

    // ---- hidden projection MFMAs ----
    if (hv) {
      const bool am = (start_a < t);
      union { u32x4 u; bf16x8 v; } c0, c1, c2, c3;
      const u32x4 zz = {0, 0, 0, 0};
      c0.u = am ? a0 : zz; c1.u = am ? a1 : zz; c2.u = am ? a2 : zz; c3.u = am ? a3 : zz;
      ar  = MFMA16(c0.v, whf[0][0], ar);  az  = MFMA16(c0.v, whf[1][0], az);
      anh = MFMA16(c0.v, whf[2][0], anh);
      ar  = MFMA16(c1.v, whf[0][1], ar);  az  = MFMA16(c1.v, whf[1][1], az);
      anh = MFMA16(c1.v, whf[2][1], anh);
      ar  = MFMA16(c2.v, whf[0][2], ar);  az  = MFMA16(c2.v, whf[1][2], az);
      anh = MFMA16(c2.v, whf[2][2], anh);
      ar  = MFMA16(c3.v, whf[0][3], ar);  az  = MFMA16(c3.v, whf[1][3], az);
      anh = MFMA16(c3.v, whf[2][3], anh);
    }

    // ---- reduce (R6 swizzled layout, 0 conflicts) + gates ----
    const int par = t & 1;
    #pragma unroll
    for (int i = 0; i < 4; ++i) {
      const int r_ = (lane >> 4) * 4 + i;
      const int c_ = (jw * 16 + (lane & 15)) ^ (((lane >> 4) & 1) << 4);
      red[par][0][kw][r_][c_] = ar[i];
      red[par][1][kw][r_][c_] = az[i];
      if constexpr (XP) {
        red[par][2][kw][r_][c_] = anh[i];
      } else {
        red[par][2][kw][r_][c_] = anx[i];
        red[par][3][kw][r_][c_] = anh[i];
      }
    }
    __syncthreads();
    float sr, sz, snx, snh;
    if constexpr (XP) { sr = lo2f(crz); sz = hi2f(crz); snx = lo2f(cn); snh = bias_nh; }
    else              { sr = bias_r;    sz = bias_z;    snx = bias_nx;  snh = bias_nh; }
    #pragma unroll
    for (int k2 = 0; k2 < 4; ++k2) {
      sr += red[par][0][k2][bq][jr];
      sz += red[par][1][k2][bq][jr];
      if constexpr (XP) {
        snh += red[par][2][k2][bq][jr];
      } else {
        snx += red[par][2][k2][bq][jr];
        snh += red[par][3][k2][bq][jr];
      }
    }
    const float r  = 1.f / (1.f + __expf(-sr));
    const float z  = 1.f / (1.f + __expf(-sz));
    const float ea = __expf(2.f * (snx + r * snh));
    const float n  = 1.f - 2.f / (ea + 1.f);             // NaN-safe tanh
    const float hm = (start_g < t) ? h_own : 0.f;
    const float hn = (1.f - z) * n + z * hm;
    h_own = hn;

    // ---- pack + single publish of gen t+1 (mode-selected ring) ----
    const unsigned ptag01 = (unsigned)(((t + 1) >> 1) & 1) * 0x00010001u;
    const float hpart = asf((unsigned)__shfl_xor((int)asu(hn), 1, 64));
    unsigned packed;
    asm("v_cvt_pk_bf16_f32 %0, %1, %2" : "=v"(packed) : "v"(hn), "v"(hpart));
    packed = (packed & 0xFFFEFFFEu) | ptag01;
    if (!(jj & 1)) {
      const size_t doff = (size_t)((t + 1) & 1) * (Bn * Hn / 2) + ((bq * Hn + jg) >> 1);
      if (fast) {
        unsigned* dstF = ringF + doff;
        asm volatile("global_store_dword %0, %1, off" :: "v"(dstF), "v"(packed) : "memory");
      } else {
        unsigned* dstS = ringS + doff;
        asm volatile("global_store_dword %0, %1, off sc0 sc1" :: "v"(dstS), "v"(packed) : "memory");
      }
    }

    po0u = asu(xres_t + hn);
    po1u = asu(hn);
  };

  #pragma unroll 1
  for (int t = 0; t < Tn; t += 4) {
    step(t + 0, prz0, pn0, pxr0, prz2, pn2, pxr2, xa0, xr0);
    step(t + 1, prz1, pn1, pxr1, prz3, pn3, pxr3, xa1, xr1);
    step(t + 2, prz2, pn2, pxr2, prz0, pn0, pxr0, xa0, xr0);
    step(t + 3, prz3, pn3, pxr3, prz1, pn1, pxr1, xa1, xr1);
  }
  {   // final outputs (t = Tn-1)
    const size_t poo = ((size_t)bq * Tn + (Tn - 1)) * Hn + jg;
    out[poo] = asf(po0u);
    out[(size_t)Bn * Tn * Hn + poo] = asf(po1u);
  }
}

extern "C" void kernel_launch(void* const* d_in, const int* in_sizes, int n_in,
                              void* d_out, int out_size, void* d_ws, size_t ws_size,
                              hipStream_t stream) {
  const float* x     = (const float*)d_in[0];
  const int*   start = (const int*)d_in[1];
  const float* w_ih  = (const float*)d_in[2];
  const float* w_hh  = (const float*)d_in[3];
  const float* b_ih  = (const float*)d_in[4];
  const float* b_hh  = (const float*)d_in[5];
  float* out = (float*)d_out;

  // ws: [0,4K) ectl | [4K,+32K) fast ring | [36K,+32K) slow ring | [128K,+64M) xrz | +32M xnb
  unsigned* ectl  = (unsigned*)d_ws;
  unsigned* ringF = (unsigned*)((char*)d_ws + 4096);
  unsigned* ringS = (unsigned*)((char*)d_ws + 36864);
  const size_t xrz_off   = 131072;
  const size_t xrz_bytes = (size_t)NWG * Tn * 512 * 4;   // 64 MiB
  const size_t xn_bytes  = (size_t)NWG * Tn * 512 * 2;   // 32 MiB
  unsigned*       xrz = (unsigned*)((char*)d_ws + xrz_off);
  unsigned short* xnb = (unsigned short*)((char*)d_ws + xrz_off + xrz_bytes);
  const bool xp = ws_size >= xrz_off + xrz_bytes + xn_bytes;

  // Parity init per ring: buf0 LSB=0 (first read t=2 expects 1), buf1 LSB=1
  // (first read t=1 expects 0). Stale replay generations (2047 tag1 / 2048
  // tag0) never false-validate at t=1/2 regardless of L2/LLC state.
  // Election/probe state zeroed each launch. All graph-capture-safe.
  hipMemsetAsync(d_ws, 0x00, 4096, stream);
  hipMemsetAsync((char*)d_ws + 4096,  0x00, 16384, stream);
  hipMemsetAsync((char*)d_ws + 20480, 0x01, 16384, stream);
  hipMemsetAsync((char*)d_ws + 36864, 0x00, 16384, stream);
  hipMemsetAsync((char*)d_ws + 53248, 0x01, 16384, stream);
  if (xp) {
    hipLaunchKernelGGL(xproj_pass, dim3(NWG, Tn / TC1), dim3(NTH), 0, stream,
                       x, w_ih, b_ih, b_hh, xrz, xnb);
    hipLaunchKernelGGL(gru_scan<true>, dim3(NLAUNCH), dim3(NTH), 0, stream,
                       x, start, w_ih, w_hh, b_ih, b_hh, out, ectl, ringF, ringS, xrz, xnb);
  } else {
    hipLaunchKernelGGL(gru_scan<false>, dim3(NLAUNCH), dim3(NTH), 0, stream,
                       x, start, w_ih, w_hh, b_ih, b_hh, out, ectl, ringF, ringS,
                       (const unsigned*)d_ws, (const unsigned short*)d_ws);
  }
}